// Round 1
// baseline (3487.151 us; speedup 1.0000x reference)
//
#include <hip/hip_runtime.h>

typedef __attribute__((ext_vector_type(4))) float f32x4;
typedef __attribute__((ext_vector_type(8))) short bf16x8;

#define T_DIM 128
#define B_DIM 32
#define H_DIM 1024
#define V_DIM 32000
#define MROWS 4096  // T*B

__device__ __forceinline__ ushort f2bf(float f){
  union { float f; unsigned u; } x; x.f = f;
  unsigned u = x.u;
  unsigned r = (u + 0x7fffu + ((u >> 16) & 1u)) >> 16;
  return (ushort)r;
}
__device__ __forceinline__ float bf2f(ushort h){
  union { unsigned u; float f; } x; x.u = ((unsigned)h) << 16;
  return x.f;
}

__device__ __forceinline__ void async_copy16(void* lds, const void* g){
  __builtin_amdgcn_global_load_lds((const __attribute__((address_space(1))) void*)g,
                                   (__attribute__((address_space(3))) void*)lds, 16, 0, 0);
}

// ---------------- casts ----------------
__global__ void cast_bf16_kernel(const float* __restrict__ s, ushort* __restrict__ d, int n4){
  int stride = gridDim.x * blockDim.x;
  for (int i = blockIdx.x*blockDim.x + threadIdx.x; i < n4; i += stride){
    float4 v = ((const float4*)s)[i];
    ushort4 o = make_ushort4(f2bf(v.x), f2bf(v.y), f2bf(v.z), f2bf(v.w));
    ((ushort4*)d)[i] = o;
  }
}

// hi = bf16(v); lo = bf16(v - hi)  (split-bf16 for near-fp32 MFMA accuracy)
__global__ void cast_split_kernel(const float* __restrict__ s, ushort* __restrict__ dh,
                                  ushort* __restrict__ dl, int n4){
  int stride = gridDim.x * blockDim.x;
  for (int i = blockIdx.x*blockDim.x + threadIdx.x; i < n4; i += stride){
    float4 v = ((const float4*)s)[i];
    ushort4 h = make_ushort4(f2bf(v.x), f2bf(v.y), f2bf(v.z), f2bf(v.w));
    ushort4 l = make_ushort4(f2bf(v.x - bf2f(h.x)), f2bf(v.y - bf2f(h.y)),
                             f2bf(v.z - bf2f(h.z)), f2bf(v.w - bf2f(h.w)));
    ((ushort4*)dh)[i] = h;
    ((ushort4*)dl)[i] = l;
  }
}

// ---------------- m97-style bf16 GEMM: C[M][N] = A[M][K] * B[N][K]^T ----------------
// optional beta accumulate into C, optional bias[n]. M = gridDim/NTN * 128 (exact tiles).
__global__ __launch_bounds__(256) void gemm_bt(
    const ushort* __restrict__ A, const ushort* __restrict__ B,
    float* __restrict__ C, const float* __restrict__ bias,
    int N, int K, int NTN, int beta)
{
  __shared__ ushort lA[128*32];
  __shared__ ushort lB[128*32];
  int tid = threadIdx.x;
  int lane = tid & 63, wid = tid >> 6;
  int tm = blockIdx.x / NTN, tn = blockIdx.x % NTN;
  int row0 = tm << 7, col0 = tn << 7;

  f32x4 acc[4][4] = {};

  auto stage = [&](const ushort* __restrict__ g, ushort* l, int r0, int k0){
    int c = wid << 1;  // each wave stages 2 chunks of 16 rows x 32 cols
    const ushort* s0 = g + (size_t)(r0 + (c<<4) + (lane>>2))*K + k0 + ((lane&3)<<3);
    async_copy16(l + (c<<9), s0);
    async_copy16(l + ((c+1)<<9), s0 + (size_t)16*K);
  };

  int nk = K >> 5;
  stage(A, lA, row0, 0);
  stage(B, lB, col0, 0);
  int wm = (wid >> 1) << 6, wn = (wid & 1) << 6;
  int kg = (lane >> 4) << 3;
  int ar = lane & 15;

  for (int kt = 0; kt < nk; ++kt){
    __syncthreads();  // drains this wave's global_load_lds (vmcnt) + barrier
    bf16x8 af[4], bfr[4];
    #pragma unroll
    for (int mi = 0; mi < 4; ++mi) af[mi]  = *(const bf16x8*)&lA[(wm + mi*16 + ar)*32 + kg];
    #pragma unroll
    for (int ni = 0; ni < 4; ++ni) bfr[ni] = *(const bf16x8*)&lB[(wn + ni*16 + ar)*32 + kg];
    #pragma unroll
    for (int mi = 0; mi < 4; ++mi)
      #pragma unroll
      for (int ni = 0; ni < 4; ++ni)
        acc[mi][ni] = __builtin_amdgcn_mfma_f32_16x16x32_bf16(af[mi], bfr[ni], acc[mi][ni], 0, 0, 0);
    if (kt + 1 < nk){
      __syncthreads();  // all waves done reading LDS before restage
      stage(A, lA, row0, (kt+1) << 5);
      stage(B, lB, col0, (kt+1) << 5);
    }
  }

  int rr = (lane >> 4) << 2;
  #pragma unroll
  for (int mi = 0; mi < 4; ++mi){
    #pragma unroll
    for (int ni = 0; ni < 4; ++ni){
      int r  = row0 + wm + mi*16 + rr;
      int cc = col0 + wn + ni*16 + ar;
      float bb = bias ? bias[cc] : 0.f;
      #pragma unroll
      for (int q = 0; q < 4; ++q){
        size_t idx = (size_t)(r + q) * N + cc;
        float prev = beta ? C[idx] : 0.f;
        C[idx] = prev + acc[mi][ni][q] + bb;
      }
    }
  }
}

// ---------------- recurrence: one launch per timestep ----------------
// gates = sigmoid(c @ Wc^T + b + ixfx_t); c_new = i*x_t + f*c
// split-bf16 operands for the c@Wc^T product (3 MFMA products; Al*Bl dropped).
__global__ __launch_bounds__(256) void ran_step(
    const ushort* __restrict__ ah, const ushort* __restrict__ al,
    const float* __restrict__ cf_in,
    const ushort* __restrict__ wh, const ushort* __restrict__ wl,
    const float* __restrict__ b_i, const float* __restrict__ b_f,
    const float* __restrict__ ixfx_t, const float* __restrict__ x_t,
    float* __restrict__ cf_out, ushort* __restrict__ cl_out,
    ushort* __restrict__ out_t)
{
  __shared__ float gsm[2*32*16];
  int tid = threadIdx.x, lane = tid & 63, wid = tid >> 6;
  int gate = wid >> 1, mh = wid & 1;
  int nb = blockIdx.x << 4;             // 16 gate-outputs per block
  int ar = lane & 15;
  int kg = (lane >> 4) << 3;
  const ushort* arow_h = ah + (size_t)((mh<<4) + ar) * H_DIM;
  const ushort* arow_l = al + (size_t)((mh<<4) + ar) * H_DIM;
  const ushort* brow_h = wh + (size_t)((gate<<10) + nb + ar) * H_DIM;
  const ushort* brow_l = wl + (size_t)((gate<<10) + nb + ar) * H_DIM;
  f32x4 acc = {};
  #pragma unroll 4
  for (int kk = 0; kk < 32; ++kk){
    int o = (kk<<5) + kg;
    bf16x8 a_h = *(const bf16x8*)&arow_h[o];
    bf16x8 a_l = *(const bf16x8*)&arow_l[o];
    bf16x8 b_h = *(const bf16x8*)&brow_h[o];
    bf16x8 b_l = *(const bf16x8*)&brow_l[o];
    acc = __builtin_amdgcn_mfma_f32_16x16x32_bf16(a_h, b_h, acc, 0, 0, 0);
    acc = __builtin_amdgcn_mfma_f32_16x16x32_bf16(a_h, b_l, acc, 0, 0, 0);
    acc = __builtin_amdgcn_mfma_f32_16x16x32_bf16(a_l, b_h, acc, 0, 0, 0);
  }
  const float* bias = gate ? b_f : b_i;
  int kgl = nb + ar;
  #pragma unroll
  for (int q = 0; q < 4; ++q){
    int m = (mh<<4) + ((lane>>4)<<2) + q;
    float pre = acc[q] + bias[kgl] + ixfx_t[m*2048 + (gate<<10) + kgl];
    float s = 1.f / (1.f + expf(-pre));
    gsm[((gate<<5) + m)*16 + ar] = s;
  }
  __syncthreads();
  for (int idx = tid; idx < 512; idx += 256){
    int m = idx >> 4, k2 = idx & 15;
    int col = nb + k2;
    float iv = gsm[(m<<4) + k2];
    float fv = gsm[((32 + m)<<4) + k2];
    float co = cf_in[(m<<10) + col];
    float xv = x_t[(m<<10) + col];
    float cn = iv * xv + fv * co;
    cf_out[(m<<10) + col] = cn;
    ushort hi = f2bf(cn);
    out_t[(m<<10) + col] = hi;                    // doubles as next step's A-hi
    cl_out[(m<<10) + col] = f2bf(cn - bf2f(hi));  // A-lo residual
  }
}

__global__ void init_c_kernel(const float* __restrict__ hidden, float* __restrict__ cf,
                              ushort* __restrict__ ch, ushort* __restrict__ cl){
  int i = blockIdx.x * blockDim.x + threadIdx.x;
  float v = hidden[i];
  cf[i] = v;
  ushort h = f2bf(v);
  ch[i] = h;
  cl[i] = f2bf(v - bf2f(h));
}

// ---------------- log_softmax over V=32000, in place ----------------
__global__ __launch_bounds__(256) void lsm_kernel(float* __restrict__ logits){
  __shared__ float sm[8];
  size_t row = blockIdx.x;
  float* p = logits + row * (size_t)V_DIM;
  const float4* p4 = (const float4*)p;
  int tid = threadIdx.x;
  float mx = -1e30f;
  for (int i = tid; i < V_DIM/4; i += 256){
    float4 v = p4[i];
    mx = fmaxf(fmaxf(mx, fmaxf(v.x, v.y)), fmaxf(v.z, v.w));
  }
  #pragma unroll
  for (int o = 32; o; o >>= 1) mx = fmaxf(mx, __shfl_xor(mx, o));
  if ((tid & 63) == 0) sm[tid >> 6] = mx;
  __syncthreads();
  if (tid == 0) sm[0] = fmaxf(fmaxf(sm[0], sm[1]), fmaxf(sm[2], sm[3]));
  __syncthreads();
  mx = sm[0];
  float s = 0.f;
  for (int i = tid; i < V_DIM/4; i += 256){
    float4 v = p4[i];
    s += expf(v.x - mx) + expf(v.y - mx) + expf(v.z - mx) + expf(v.w - mx);
  }
  #pragma unroll
  for (int o = 32; o; o >>= 1) s += __shfl_xor(s, o);
  if ((tid & 63) == 0) sm[4 + (tid >> 6)] = s;
  __syncthreads();
  if (tid == 0) sm[4] = sm[4] + sm[5] + sm[6] + sm[7];
  __syncthreads();
  float lse = mx + logf(sm[4]);
  float4* q4 = (float4*)p;
  for (int i = tid; i < V_DIM/4; i += 256){
    float4 v = q4[i];
    v.x -= lse; v.y -= lse; v.z -= lse; v.w -= lse;
    q4[i] = v;
  }
}

__global__ void copy_f32_kernel(const float* __restrict__ s, float* __restrict__ d, int n){
  int i = blockIdx.x * blockDim.x + threadIdx.x;
  if (i < n) d[i] = s[i];
}

// ---------------- launch ----------------
extern "C" void kernel_launch(void* const* d_in, const int* in_sizes, int n_in,
                              void* d_out, int out_size, void* d_ws, size_t ws_size,
                              hipStream_t stream)
{
  const float* input  = (const float*)d_in[0];
  const float* hidden = (const float*)d_in[1];
  const float* w_ic   = (const float*)d_in[2];
  const float* w_ix   = (const float*)d_in[3];
  const float* w_fc   = (const float*)d_in[4];
  const float* w_fx   = (const float*)d_in[5];
  const float* b_i    = (const float*)d_in[6];
  const float* b_f    = (const float*)d_in[7];
  const float* W_out  = (const float*)d_in[8];
  const float* b_out  = (const float*)d_in[9];
  float* out = (float*)d_out;

  char* ws = (char*)d_ws;
  ushort* wout_bf = (ushort*)(ws + 0);          // 65,536,000 B
  ushort* in_hi   = (ushort*)(ws + 65536000);   // 8,388,608 B
  ushort* in_lo   = (ushort*)(ws + 73924608);
  ushort* wx_hi   = (ushort*)(ws + 82313216);   // [w_ix; w_fx] 4,194,304 B
  ushort* wx_lo   = (ushort*)(ws + 86507520);
  ushort* wc_hi   = (ushort*)(ws + 90701824);   // [w_ic; w_fc]
  ushort* wc_lo   = (ushort*)(ws + 94896128);
  ushort* out_bf  = (ushort*)(ws + 99090432);   // all T outputs, bf16(c) 8,388,608 B
  float*  cf0     = (float*) (ws + 107479040);
  float*  cf1     = (float*) (ws + 107610112);
  ushort* ch_init = (ushort*)(ws + 107741184);
  ushort* cl0     = (ushort*)(ws + 107872256);
  ushort* cl1     = (ushort*)(ws + 107937792);
  float* ixfx = out;  // [4096][2048] scratch in the (later overwritten) logits region

  cast_bf16_kernel <<<2048,256,0,stream>>>(W_out, wout_bf, V_DIM*H_DIM/4);
  cast_split_kernel<<<1024,256,0,stream>>>(input, in_hi, in_lo, MROWS*H_DIM/4);
  cast_split_kernel<<<256,256,0,stream>>>(w_ix, wx_hi,             wx_lo,             H_DIM*H_DIM/4);
  cast_split_kernel<<<256,256,0,stream>>>(w_fx, wx_hi+H_DIM*H_DIM, wx_lo+H_DIM*H_DIM, H_DIM*H_DIM/4);
  cast_split_kernel<<<256,256,0,stream>>>(w_ic, wc_hi,             wc_lo,             H_DIM*H_DIM/4);
  cast_split_kernel<<<256,256,0,stream>>>(w_fc, wc_hi+H_DIM*H_DIM, wc_lo+H_DIM*H_DIM, H_DIM*H_DIM/4);

  // ixfx = input @ [w_ix; w_fx]^T  (split-bf16: Ah*Bh + Ah*Bl + Al*Bh)
  gemm_bt<<<32*16,256,0,stream>>>(in_hi, wx_hi, ixfx, nullptr, 2048, H_DIM, 16, 0);
  gemm_bt<<<32*16,256,0,stream>>>(in_hi, wx_lo, ixfx, nullptr, 2048, H_DIM, 16, 1);
  gemm_bt<<<32*16,256,0,stream>>>(in_lo, wx_hi, ixfx, nullptr, 2048, H_DIM, 16, 1);

  init_c_kernel<<<128,256,0,stream>>>(hidden, cf0, ch_init, cl0);

  for (int t = 0; t < T_DIM; ++t){
    const ushort* ah = (t == 0) ? ch_init : (out_bf + (size_t)(t-1)*B_DIM*H_DIM);
    const ushort* al = (t & 1) ? cl1 : cl0;
    const float*  ci = (t & 1) ? cf1 : cf0;
    float*  co = (t & 1) ? cf0 : cf1;
    ushort* lo = (t & 1) ? cl0 : cl1;
    ran_step<<<64,256,0,stream>>>(ah, al, ci, wc_hi, wc_lo, b_i, b_f,
        ixfx + (size_t)t*B_DIM*2048, input + (size_t)t*B_DIM*H_DIM,
        co, lo, out_bf + (size_t)t*B_DIM*H_DIM);
  }

  // logits = outputs @ W_out^T + b_out  -> d_out (plain bf16)
  gemm_bt<<<32*250,256,0,stream>>>(out_bf, wout_bf, out, b_out, V_DIM, H_DIM, 250, 0);
  lsm_kernel<<<4096,256,0,stream>>>(out);
  // t=127 wrote cf0
  copy_f32_kernel<<<128,256,0,stream>>>(cf0, out + (size_t)MROWS*V_DIM, B_DIM*H_DIM);
}